// Round 9
// baseline (144.082 us; speedup 1.0000x reference)
//
#include <hip/hip_runtime.h>

// KruskalLinearLayer — FUSED, ONE ROW PER WAVE, LDS off-loaded, CACHED stores,
// DEFERRED BARRIER (R9).
//   y[n,abc] = sum_r g0[a,r]g1[b,r]g2[c,r] * S[n,r] + bias[abc]
//   S[n,r]   = sum_{d,e,f} g3[d,r]g4[e,r]g5[f,r] * x[n,def]
//   g_m = f_m @ c_m  (16x8 @ 8x16)
//
// R12 (cached stores) gained 3.5us -> kernel ~30us vs ~19.5us traffic floor.
// Remaining gap: ~3.4us dispatch overhead (measured, stays - R6->R7 proved
// folding gmat back is a net loss), ~2us middle bubble, ~2-3us ramp.
// R9 attacks the RAMP, zero structural risk:
//  (1) first 8 x-loads issued BEFORE LDS staging (first HBM request at
//      kernel instruction ~5, not after stage+barrier);
//  (2) __syncthreads() DEFERRED to after the d-loop — the d-loop reads
//      only gw (global uniform) and x; wlds is first read in the
//      epilogue. Staging writes complete under the d-loop for free.
//      (n clamped to N-1 instead of early-return so barrier is uniform.)
//  (3) phase-2 chunk loop unroll 2 -> 4 (deeper store/load interleave).
// Everything else identical to R12: gmat pre-kernel -> gw in d_ws,
// uniform global g3q/g0q reads, xa/xb ping-pong NT loads, t-accumulator
// d-loop (remat-proof), 33-op shuffle allreduce, cached output stores.

typedef float f32x4 __attribute__((ext_vector_type(4)));

#define WPB 4   // waves per block

// ws float-offsets for the g tables
//   [0]    g3[d][r]   (uniform quads for phase 1)
//   [256]  g0[a][r]   (uniform quads for phase 2)
//   [512]  g4t[r][e]  (lane-varying -> LDS)
//   [768]  g5t[r][f]
//   [1024] g1t[r][b]
//   [1280] g2t[r][c]

__global__ __launch_bounds__(256)
void kruskal_gmat(const float* __restrict__ c0, const float* __restrict__ c1,
                  const float* __restrict__ c2, const float* __restrict__ c3,
                  const float* __restrict__ c4, const float* __restrict__ c5,
                  const float* __restrict__ f0, const float* __restrict__ f1,
                  const float* __restrict__ f2, const float* __restrict__ f3,
                  const float* __restrict__ f4, const float* __restrict__ f5,
                  float* __restrict__ gw)
{
    const int t = threadIdx.x;
    const int i = t >> 4, r = t & 15;
    float a0 = 0.f, a1 = 0.f, a2 = 0.f, a3 = 0.f, a4 = 0.f, a5 = 0.f;
#pragma unroll
    for (int k = 0; k < 8; ++k) {
        a0 += f0[i * 8 + k] * c0[k * 16 + r];
        a1 += f1[i * 8 + k] * c1[k * 16 + r];
        a2 += f2[i * 8 + k] * c2[k * 16 + r];
        a3 += f3[i * 8 + k] * c3[k * 16 + r];
        a4 += f4[i * 8 + k] * c4[k * 16 + r];
        a5 += f5[i * 8 + k] * c5[k * 16 + r];
    }
    gw[         i * 16 + r] = a3;   // g3[d][r]
    gw[ 256 +   i * 16 + r] = a0;   // g0[a][r]
    gw[ 512 +   r * 16 + i] = a4;   // g4t[r][e]
    gw[ 768 +   r * 16 + i] = a5;   // g5t[r][f]
    gw[1024 +   r * 16 + i] = a1;   // g1t[r][b]
    gw[1280 +   r * 16 + i] = a2;   // g2t[r][c]
}

__global__ __launch_bounds__(256, 2)
void kruskal_fused(const float* __restrict__ x,
                   const float* __restrict__ gw,
                   const float* __restrict__ bias,
                   float* __restrict__ out, int N)
{
    // Only the LANE-VARYING tables live in LDS (4 x 256 floats = 4 KB).
    __shared__ __align__(16) float wlds[1024];  // [g4t | g5t | g1t | g2t]

    const int tid = threadIdx.x;
    const int lane = tid & 63, waveId = tid >> 6;
    const int eb  = lane >> 2;         // e (phase1) / b (phase2)
    const int fcb = (lane & 3) * 4;    // f base     / c base

    const int n = blockIdx.x * WPB + waveId;   // ONE row per wave
    // Clamp instead of early-return: keeps the (deferred) barrier uniform
    // across the block. For N=4096 the clamp never fires.
    const int nrow = (n < N) ? n : (N - 1);
    const float* xn = x + (size_t)nrow * 4096 + lane * 4;

#define LOAD4(v, dbase)                                                       \
    v##0 = __builtin_nontemporal_load((const f32x4*)(xn + ((dbase) + 0) * 256)); \
    v##1 = __builtin_nontemporal_load((const f32x4*)(xn + ((dbase) + 1) * 256)); \
    v##2 = __builtin_nontemporal_load((const f32x4*)(xn + ((dbase) + 2) * 256)); \
    v##3 = __builtin_nontemporal_load((const f32x4*)(xn + ((dbase) + 3) * 256));

#define COMP1(xv, d)                                                          \
    {                                                                         \
        _Pragma("unroll")                                                     \
        for (int rq = 0; rq < 4; ++rq) {                                      \
            const f32x4 g3q = *(const f32x4*)(gw + (d) * 16 + rq * 4);        \
            _Pragma("unroll")                                                 \
            for (int rr = 0; rr < 4; ++rr)                                    \
                t[rq * 4 + rr] += g3q[rr] * xv;                               \
        }                                                                     \
    }

#define COMP4(v, dbase)                                                       \
    COMP1(v##0, (dbase) + 0) COMP1(v##1, (dbase) + 1)                         \
    COMP1(v##2, (dbase) + 2) COMP1(v##3, (dbase) + 3)

    // (1) FIRST: put 8 KB of x-loads in flight before anything else.
    f32x4 xa0, xa1, xa2, xa3, xb0, xb1, xb2, xb3;
    LOAD4(xa, 0)
    LOAD4(xb, 4)

    // (2) LDS staging — one f32x4 per thread; barrier DEFERRED (d-loop
    // never reads wlds, so staging completes under the d-loop).
    {
        const f32x4* src = (const f32x4*)(gw + 512);
        ((f32x4*)wlds)[tid] = src[tid];
    }

    // ---- phase 1: t[r] = sum_d g3[d][r] * xd   (f32x4 accumulators) ----
    // g3 quads are wave-uniform GLOBAL reads; zero LDS ops in the loop.
    f32x4 t[16];
#pragma unroll
    for (int r = 0; r < 16; ++r) t[r] = f32x4{0.f, 0.f, 0.f, 0.f};

    COMP4(xa, 0)
    LOAD4(xa, 8)
    COMP4(xb, 4)
    LOAD4(xb, 12)
    COMP4(xa, 8)
    COMP4(xb, 12)
#undef LOAD4
#undef COMP1
#undef COMP4

    // Fence + deferred barrier: wlds guaranteed written block-wide here.
    __builtin_amdgcn_sched_barrier(0);
    __syncthreads();

    // ---- phase-1 epilogue: s[r] = w1[r] . t[r]  (w1 lives ~1 instr) ----
    float s[16];
#pragma unroll
    for (int r = 0; r < 16; ++r) {
        const f32x4 w = (*(const f32x4*)&wlds[256 + r * 16 + fcb])  // g5t
                      * wlds[r * 16 + eb];                          // g4t
        s[r] = w.x * t[r].x + w.y * t[r].y + w.z * t[r].z + w.w * t[r].w;
    }

    // ---- allreduce: reduce-scatter (15) + butterfly (2) + allgather (16) ----
    float k8[8];
    {
        const bool b = lane & 1;
#pragma unroll
        for (int j = 0; j < 8; ++j) {
            const float snd = b ? s[2 * j] : s[2 * j + 1];
            const float prt = __shfl_xor(snd, 1, 64);
            const float kp  = b ? s[2 * j + 1] : s[2 * j];
            k8[j] = kp + prt;                                // r = (j<<1)|lane0
        }
    }
    float k4[4];
    {
        const bool b = (lane >> 1) & 1;
#pragma unroll
        for (int j = 0; j < 4; ++j) {
            const float snd = b ? k8[2 * j] : k8[2 * j + 1];
            const float prt = __shfl_xor(snd, 2, 64);
            const float kp  = b ? k8[2 * j + 1] : k8[2 * j];
            k4[j] = kp + prt;                                // r = (j<<2)|(lane&3)
        }
    }
    float k2[2];
    {
        const bool b = (lane >> 2) & 1;
#pragma unroll
        for (int j = 0; j < 2; ++j) {
            const float snd = b ? k4[2 * j] : k4[2 * j + 1];
            const float prt = __shfl_xor(snd, 4, 64);
            const float kp  = b ? k4[2 * j + 1] : k4[2 * j];
            k2[j] = kp + prt;                                // r = (j<<3)|(lane&7)
        }
    }
    float k1;
    {
        const bool b = (lane >> 3) & 1;
        const float snd = b ? k2[0] : k2[1];
        const float prt = __shfl_xor(snd, 8, 64);
        const float kp  = b ? k2[1] : k2[0];
        k1 = kp + prt;                                       // r = lane&15
    }
    k1 += __shfl_xor(k1, 16, 64);
    k1 += __shfl_xor(k1, 32, 64);                            // full 64-lane sum
    const int gbase = lane & 48;
#pragma unroll
    for (int r = 0; r < 16; ++r)
        s[r] = __shfl(k1, gbase | r, 64);

    // Fence: keep sw's LDS reads from drifting up past the allreduce.
    __builtin_amdgcn_sched_barrier(0);

    // ---- phase-2: sw[r] = g2vec * g1 * S[r]; then pure-FMA chunk loop ----
    f32x4 sw[16];
#pragma unroll
    for (int r = 0; r < 16; ++r)
        sw[r] = (*(const f32x4*)&wlds[768 + r * 16 + fcb])          // g2t
              * (wlds[512 + r * 16 + eb] * s[r]);                   // g1t
    // g0 quads: wave-uniform global reads; bias: direct global (L1/L2-hot).
    const float* bl = bias + lane * 4;
    float* on = out + (size_t)nrow * 4096;
    if (n < N) {
#pragma unroll 4
        for (int a = 0; a < 16; ++a) {
            f32x4 acc = *(const f32x4*)(bl + a * 256);
#pragma unroll
            for (int rq = 0; rq < 4; ++rq) {
                const f32x4 g0q = *(const f32x4*)(gw + 256 + a * 16 + rq * 4);
#pragma unroll
                for (int rr = 0; rr < 4; ++rr)
                    acc += g0q[rr] * sw[rq * 4 + rr];
            }
            // cached store (R12 win: no write amplification, L3 buffering)
            *(f32x4*)(on + a * 256 + lane * 4) = acc;
        }
    }
}

extern "C" void kernel_launch(void* const* d_in, const int* in_sizes, int n_in,
                              void* d_out, int out_size, void* d_ws, size_t ws_size,
                              hipStream_t stream) {
    const float* x  = (const float*)d_in[0];
    const float* c0 = (const float*)d_in[1];
    const float* c1 = (const float*)d_in[2];
    const float* c2 = (const float*)d_in[3];
    const float* c3 = (const float*)d_in[4];
    const float* c4 = (const float*)d_in[5];
    const float* c5 = (const float*)d_in[6];
    const float* f0 = (const float*)d_in[7];
    const float* f1 = (const float*)d_in[8];
    const float* f2 = (const float*)d_in[9];
    const float* f3 = (const float*)d_in[10];
    const float* f4 = (const float*)d_in[11];
    const float* f5 = (const float*)d_in[12];
    const float* bias = (const float*)d_in[13];
    float* out = (float*)d_out;
    float* gw  = (float*)d_ws;          // 1536 floats = 6 KB

    const int N = in_sizes[0] / 4096;
    const int blocks = (N + WPB - 1) / WPB;   // one row per wave

    kruskal_gmat<<<dim3(1), dim3(256), 0, stream>>>(
        c0, c1, c2, c3, c4, c5, f0, f1, f2, f3, f4, f5, gw);
    kruskal_fused<<<dim3(blocks), dim3(256), 0, stream>>>(
        x, gw, bias, out, N);
}

// Round 10
// 141.385 us; speedup vs baseline: 1.0191x; 1.0191x over previous
//
#include <hip/hip_runtime.h>

// KruskalLinearLayer — FUSED, ONE ROW PER WAVE, LDS off-loaded, CACHED stores,
// READLANE allgather (R10 = R8 + one micro-change).
//   y[n,abc] = sum_r g0[a,r]g1[b,r]g2[c,r] * S[n,r] + bias[abc]
//   S[n,r]   = sum_{d,e,f} g3[d,r]g4[e,r]g5[f,r] * x[n,def]
//   g_m = f_m @ c_m  (16x8 @ 8x16)
//
// R9 post-mortem: the 3-change bundle (early loads / deferred barrier /
// unroll 4) regressed +2.1us — vmcnt is IN-ORDER, so the staging ds_write
// (dependent on a gw load issued after 8 x-loads) serialized behind the
// whole prefetch. All three reverted; structure below is byte-identical
// to R8 except the allgather.
// R10 single change: after the butterfly, k1 at lane r IS the full
// 64-lane sum of S[r] (wave-uniform). The 16-op ds_bpermute allgather
// (LDS pipe — the congested resource per R6/R7) is replaced with 16
// v_readlane_b32 (VALU, literal lane, SGPR result): zero LDS traffic in
// the middle bubble, s[] moves to SGPRs, ~16 VGPRs freed in phase 2.

typedef float f32x4 __attribute__((ext_vector_type(4)));

#define WPB 4   // waves per block

// ws float-offsets for the g tables
//   [0]    g3[d][r]   (uniform quads for phase 1)
//   [256]  g0[a][r]   (uniform quads for phase 2)
//   [512]  g4t[r][e]  (lane-varying -> LDS)
//   [768]  g5t[r][f]
//   [1024] g1t[r][b]
//   [1280] g2t[r][c]

__global__ __launch_bounds__(256)
void kruskal_gmat(const float* __restrict__ c0, const float* __restrict__ c1,
                  const float* __restrict__ c2, const float* __restrict__ c3,
                  const float* __restrict__ c4, const float* __restrict__ c5,
                  const float* __restrict__ f0, const float* __restrict__ f1,
                  const float* __restrict__ f2, const float* __restrict__ f3,
                  const float* __restrict__ f4, const float* __restrict__ f5,
                  float* __restrict__ gw)
{
    const int t = threadIdx.x;
    const int i = t >> 4, r = t & 15;
    float a0 = 0.f, a1 = 0.f, a2 = 0.f, a3 = 0.f, a4 = 0.f, a5 = 0.f;
#pragma unroll
    for (int k = 0; k < 8; ++k) {
        a0 += f0[i * 8 + k] * c0[k * 16 + r];
        a1 += f1[i * 8 + k] * c1[k * 16 + r];
        a2 += f2[i * 8 + k] * c2[k * 16 + r];
        a3 += f3[i * 8 + k] * c3[k * 16 + r];
        a4 += f4[i * 8 + k] * c4[k * 16 + r];
        a5 += f5[i * 8 + k] * c5[k * 16 + r];
    }
    gw[         i * 16 + r] = a3;   // g3[d][r]
    gw[ 256 +   i * 16 + r] = a0;   // g0[a][r]
    gw[ 512 +   r * 16 + i] = a4;   // g4t[r][e]
    gw[ 768 +   r * 16 + i] = a5;   // g5t[r][f]
    gw[1024 +   r * 16 + i] = a1;   // g1t[r][b]
    gw[1280 +   r * 16 + i] = a2;   // g2t[r][c]
}

__global__ __launch_bounds__(256, 2)
void kruskal_fused(const float* __restrict__ x,
                   const float* __restrict__ gw,
                   const float* __restrict__ bias,
                   float* __restrict__ out, int N)
{
    // Only the LANE-VARYING tables live in LDS (4 x 256 floats = 4 KB).
    __shared__ __align__(16) float wlds[1024];  // [g4t | g5t | g1t | g2t]

    const int tid = threadIdx.x;
    {   // one f32x4 per thread: gw floats [512..1536) -> wlds
        const f32x4* src = (const f32x4*)(gw + 512);
        ((f32x4*)wlds)[tid] = src[tid];
    }
    __syncthreads();

    const int lane = tid & 63, waveId = tid >> 6;
    const int eb  = lane >> 2;         // e (phase1) / b (phase2)
    const int fcb = (lane & 3) * 4;    // f base     / c base

    const int n = blockIdx.x * WPB + waveId;   // ONE row per wave
    if (n >= N) return;
    const float* xn = x + (size_t)n * 4096 + lane * 4;

    // ---- phase 1: t[r] = sum_d g3[d][r] * xd   (f32x4 accumulators) ----
    // g3 quads are wave-uniform GLOBAL reads (s_load / L1-broadcast):
    // the hot loop issues ZERO LDS operations.
    f32x4 t[16];
#pragma unroll
    for (int r = 0; r < 16; ++r) t[r] = f32x4{0.f, 0.f, 0.f, 0.f};

#define LOAD4(v, dbase)                                                       \
    v##0 = __builtin_nontemporal_load((const f32x4*)(xn + ((dbase) + 0) * 256)); \
    v##1 = __builtin_nontemporal_load((const f32x4*)(xn + ((dbase) + 1) * 256)); \
    v##2 = __builtin_nontemporal_load((const f32x4*)(xn + ((dbase) + 2) * 256)); \
    v##3 = __builtin_nontemporal_load((const f32x4*)(xn + ((dbase) + 3) * 256));

#define COMP1(xv, d)                                                          \
    {                                                                         \
        _Pragma("unroll")                                                     \
        for (int rq = 0; rq < 4; ++rq) {                                      \
            const f32x4 g3q = *(const f32x4*)(gw + (d) * 16 + rq * 4);        \
            _Pragma("unroll")                                                 \
            for (int rr = 0; rr < 4; ++rr)                                    \
                t[rq * 4 + rr] += g3q[rr] * xv;                               \
        }                                                                     \
    }

#define COMP4(v, dbase)                                                       \
    COMP1(v##0, (dbase) + 0) COMP1(v##1, (dbase) + 1)                         \
    COMP1(v##2, (dbase) + 2) COMP1(v##3, (dbase) + 3)

    {
        // ping-pong double buffer: batch i+1's loads in flight while batch
        // i computes. Live: t(64) + xa+xb(32) + addr ~ 105 regs.
        f32x4 xa0, xa1, xa2, xa3, xb0, xb1, xb2, xb3;
        LOAD4(xa, 0)
        LOAD4(xb, 4)
        COMP4(xa, 0)
        LOAD4(xa, 8)
        COMP4(xb, 4)
        LOAD4(xb, 12)
        COMP4(xa, 8)
        COMP4(xb, 12)
    }
#undef LOAD4
#undef COMP1
#undef COMP4

    // Fence: keep the epilogue's lane-varying LDS reads OUT of the d-loop
    // region (hoisting them would recreate a 64-reg w1 array next to t).
    __builtin_amdgcn_sched_barrier(0);

    // ---- phase-1 epilogue: s[r] = w1[r] . t[r]  (w1 lives ~1 instr) ----
    float s[16];
#pragma unroll
    for (int r = 0; r < 16; ++r) {
        const f32x4 w = (*(const f32x4*)&wlds[256 + r * 16 + fcb])  // g5t
                      * wlds[r * 16 + eb];                          // g4t
        s[r] = w.x * t[r].x + w.y * t[r].y + w.z * t[r].z + w.w * t[r].w;
    }

    // ---- allreduce: reduce-scatter (15) + butterfly (2) + readlane (16) ----
    float k8[8];
    {
        const bool b = lane & 1;
#pragma unroll
        for (int j = 0; j < 8; ++j) {
            const float snd = b ? s[2 * j] : s[2 * j + 1];
            const float prt = __shfl_xor(snd, 1, 64);
            const float kp  = b ? s[2 * j + 1] : s[2 * j];
            k8[j] = kp + prt;                                // r = (j<<1)|lane0
        }
    }
    float k4[4];
    {
        const bool b = (lane >> 1) & 1;
#pragma unroll
        for (int j = 0; j < 4; ++j) {
            const float snd = b ? k8[2 * j] : k8[2 * j + 1];
            const float prt = __shfl_xor(snd, 2, 64);
            const float kp  = b ? k8[2 * j + 1] : k8[2 * j];
            k4[j] = kp + prt;                                // r = (j<<2)|(lane&3)
        }
    }
    float k2[2];
    {
        const bool b = (lane >> 2) & 1;
#pragma unroll
        for (int j = 0; j < 2; ++j) {
            const float snd = b ? k4[2 * j] : k4[2 * j + 1];
            const float prt = __shfl_xor(snd, 4, 64);
            const float kp  = b ? k4[2 * j + 1] : k4[2 * j];
            k2[j] = kp + prt;                                // r = (j<<3)|(lane&7)
        }
    }
    float k1;
    {
        const bool b = (lane >> 3) & 1;
        const float snd = b ? k2[0] : k2[1];
        const float prt = __shfl_xor(snd, 8, 64);
        const float kp  = b ? k2[1] : k2[0];
        k1 = kp + prt;                                       // r = lane&15
    }
    k1 += __shfl_xor(k1, 16, 64);
    k1 += __shfl_xor(k1, 32, 64);   // k1 @ lane l = FULL sum of S[l&15]

    // R10 single change: allgather via v_readlane (VALU->SGPR, lane r is
    // a literal) instead of 16 ds_bpermute — zero LDS ops, s[] in SGPRs.
    float s2[16];
#pragma unroll
    for (int r = 0; r < 16; ++r)
        s2[r] = __int_as_float(__builtin_amdgcn_readlane(__float_as_int(k1), r));

    // Fence: keep sw's LDS reads from drifting up past the allreduce.
    __builtin_amdgcn_sched_barrier(0);

    // ---- phase-2: sw[r] = g2vec * g1 * S[r]; then pure-FMA chunk loop ----
    f32x4 sw[16];
#pragma unroll
    for (int r = 0; r < 16; ++r)
        sw[r] = (*(const f32x4*)&wlds[768 + r * 16 + fcb])          // g2t
              * (wlds[512 + r * 16 + eb] * s2[r]);                  // g1t
    // g0 quads: wave-uniform global reads; bias: direct global (L1/L2-hot).
    const float* bl = bias + lane * 4;
    float* on = out + (size_t)n * 4096;
#pragma unroll 2
    for (int a = 0; a < 16; ++a) {
        f32x4 acc = *(const f32x4*)(bl + a * 256);
#pragma unroll
        for (int rq = 0; rq < 4; ++rq) {
            const f32x4 g0q = *(const f32x4*)(gw + 256 + a * 16 + rq * 4);
#pragma unroll
            for (int rr = 0; rr < 4; ++rr)
                acc += g0q[rr] * sw[rq * 4 + rr];
        }
        // cached store (R8 win: no write amplification, L3 buffering)
        *(f32x4*)(on + a * 256 + lane * 4) = acc;
    }
}

extern "C" void kernel_launch(void* const* d_in, const int* in_sizes, int n_in,
                              void* d_out, int out_size, void* d_ws, size_t ws_size,
                              hipStream_t stream) {
    const float* x  = (const float*)d_in[0];
    const float* c0 = (const float*)d_in[1];
    const float* c1 = (const float*)d_in[2];
    const float* c2 = (const float*)d_in[3];
    const float* c3 = (const float*)d_in[4];
    const float* c4 = (const float*)d_in[5];
    const float* c5 = (const float*)d_in[6];
    const float* f0 = (const float*)d_in[7];
    const float* f1 = (const float*)d_in[8];
    const float* f2 = (const float*)d_in[9];
    const float* f3 = (const float*)d_in[10];
    const float* f4 = (const float*)d_in[11];
    const float* f5 = (const float*)d_in[12];
    const float* bias = (const float*)d_in[13];
    float* out = (float*)d_out;
    float* gw  = (float*)d_ws;          // 1536 floats = 6 KB

    const int N = in_sizes[0] / 4096;
    const int blocks = (N + WPB - 1) / WPB;   // one row per wave

    kruskal_gmat<<<dim3(1), dim3(256), 0, stream>>>(
        c0, c1, c2, c3, c4, c5, f0, f1, f2, f3, f4, f5, gw);
    kruskal_fused<<<dim3(blocks), dim3(256), 0, stream>>>(
        x, gw, bias, out, N);
}